// Round 12
// baseline (200.393 us; speedup 1.0000x reference)
//
#include <hip/hip_runtime.h>

// x: [T=63, B=1, H=16, S=384, D=128] f32
// y: [T=63, B=1, H=16, D=128, S=384] f32
// out: [63, 1, 16, 384, 384] f32 = broadcast of per-head (mean_t x) @ (mean_t y)
#define T_DIM 63
#define H_DIM 16
#define S_DIM 384
#define D_DIM 128
#define SLICE_ELEMS (H_DIM * S_DIM * D_DIM)        // 786432 floats per t-slice
#define SLICE_F4    (SLICE_ELEMS / 4)              // 196608
#define OUT_TSTRIDE (H_DIM * S_DIM * S_DIM)        // 2359296 floats per t-slice of out
#define W_F4        (OUT_TSTRIDE / 4)              // 589824 float4 per t-slice

typedef float f32x4 __attribute__((ext_vector_type(4)));

// Kernel 1: temporal mean over T for both x and y. Pure read-bound (396 MB).
// nt loads (R7 A/B: nt worth ~15-20%). Byte-identical to R8/R10/R11.
__global__ __launch_bounds__(256) void treduce_kernel(
    const float* __restrict__ x, const float* __restrict__ y,
    float* __restrict__ xb, float* __restrict__ yb) {
  int tid = blockIdx.x * 256 + threadIdx.x;      // 0 .. 2*SLICE_F4-1
  const f32x4* src;
  f32x4* dst;
  if (tid < SLICE_F4) {
    src = reinterpret_cast<const f32x4*>(x) + tid;
    dst = reinterpret_cast<f32x4*>(xb) + tid;
  } else {
    tid -= SLICE_F4;
    src = reinterpret_cast<const f32x4*>(y) + tid;
    dst = reinterpret_cast<f32x4*>(yb) + tid;
  }
  f32x4 acc = (f32x4)0.f;
#pragma unroll 9
  for (int t = 0; t < T_DIM; ++t) {
    f32x4 v = __builtin_nontemporal_load(src + (size_t)t * SLICE_F4);
    acc += v;
  }
  acc *= (1.0f / (float)T_DIM);
  *dst = acc;
}

// Kernel 2: GEMM -> t=0 slice. NEW: 64x32 tile, 128 threads, 4 rows/thread.
// Rationale: per-thread LDS traffic (128 ds_read_b128 of B) is independent of
// rows/thread, so R=4 quarters ds-reads per output vs R10/R11's R=1.
// Per CU: 1152 blocks -> 9 waves x 1536 ds-cyc ~ 5.8 us (was ~11.5).
// A read direct from global (8-lane broadcast per rg, L1/L2-hot).
// grid = (12, 6, 16), block = 128. nt store for w (R11 win: clean k3 reads).
__global__ __launch_bounds__(128) void gemm_kernel(
    const float* __restrict__ xb, const float* __restrict__ yb,
    float* __restrict__ out) {
  __shared__ float Bs[128][36];

  const int h  = blockIdx.z;
  const int by = blockIdx.y;   // 64-row slab
  const int bx = blockIdx.x;   // 32-col slab
  const int t  = threadIdx.x;  // 0..127

  const float* A = xb + (size_t)h * S_DIM * D_DIM;  // [384][128] row-major
  const float* B = yb + (size_t)h * D_DIM * S_DIM;  // [128][384] row-major

  // Stage B tile: 128 rows x 32 cols = 1024 float4, 8 per thread.
#pragma unroll
  for (int it = 0; it < 8; ++it) {
    int l = t + it * 128;
    int k  = l >> 3;         // 8 float4 per row
    int c4 = l & 7;
    float4 v = *reinterpret_cast<const float4*>(B + (size_t)k * S_DIM + bx * 32 + c4 * 4);
    *reinterpret_cast<float4*>(&Bs[k][c4 * 4]) = v;
  }
  __syncthreads();

  const int rg = t >> 3;    // 0..15 row group
  const int c4 = t & 7;     // 0..7

  const int r0 = by * 64 + rg * 4;
  const f32x4* A0 = reinterpret_cast<const f32x4*>(A + (size_t)(r0 + 0) * D_DIM);
  const f32x4* A1 = reinterpret_cast<const f32x4*>(A + (size_t)(r0 + 1) * D_DIM);
  const f32x4* A2 = reinterpret_cast<const f32x4*>(A + (size_t)(r0 + 2) * D_DIM);
  const f32x4* A3 = reinterpret_cast<const f32x4*>(A + (size_t)(r0 + 3) * D_DIM);

  f32x4 acc0 = (f32x4)0.f, acc1 = (f32x4)0.f, acc2 = (f32x4)0.f, acc3 = (f32x4)0.f;
#pragma unroll 8
  for (int k4 = 0; k4 < 32; ++k4) {
    f32x4 b0 = *reinterpret_cast<const f32x4*>(&Bs[k4 * 4 + 0][c4 * 4]);
    f32x4 b1 = *reinterpret_cast<const f32x4*>(&Bs[k4 * 4 + 1][c4 * 4]);
    f32x4 b2 = *reinterpret_cast<const f32x4*>(&Bs[k4 * 4 + 2][c4 * 4]);
    f32x4 b3 = *reinterpret_cast<const f32x4*>(&Bs[k4 * 4 + 3][c4 * 4]);
    f32x4 a0 = A0[k4], a1 = A1[k4], a2 = A2[k4], a3 = A3[k4];
    acc0 += a0.x * b0; acc0 += a0.y * b1; acc0 += a0.z * b2; acc0 += a0.w * b3;
    acc1 += a1.x * b0; acc1 += a1.y * b1; acc1 += a1.z * b2; acc1 += a1.w * b3;
    acc2 += a2.x * b0; acc2 += a2.y * b1; acc2 += a2.z * b2; acc2 += a2.w * b3;
    acc3 += a3.x * b0; acc3 += a3.y * b1; acc3 += a3.z * b2; acc3 += a3.w * b3;
  }

  // Write ONCE into the t=0 slice — nt stores (R11: keep w clean for k3).
  float* o = out + (size_t)h * S_DIM * S_DIM + (size_t)r0 * S_DIM + bx * 32 + c4 * 4;
  __builtin_nontemporal_store(acc0, reinterpret_cast<f32x4*>(o));
  __builtin_nontemporal_store(acc1, reinterpret_cast<f32x4*>(o + S_DIM));
  __builtin_nontemporal_store(acc2, reinterpret_cast<f32x4*>(o + 2 * S_DIM));
  __builtin_nontemporal_store(acc3, reinterpret_cast<f32x4*>(o + 3 * S_DIM));
}

// Kernel 3: pure broadcast, fill geometry (t-major), FATTER BLOCKS this round:
// each block owns a 64 KB chunk (4x R8's 16 KB) of one t-slice, amortizing
// per-block dispatch + endpgm-drain cost 4x. grid = (144, 62), block = 256.
// 144 % 8 == 0 -> all 62 readers of chunk cx still land on one XCD (L2-hot).
__global__ __launch_bounds__(256) void bcast_kernel(float* __restrict__ out) {
  const int base = blockIdx.x * 4096 + threadIdx.x;      // chunk base + lane
  const size_t toff = (size_t)(blockIdx.y + 1) * W_F4;   // t = 1..62
  const f32x4* src = reinterpret_cast<const f32x4*>(out);
  f32x4* dst = reinterpret_cast<f32x4*>(out) + toff;
#pragma unroll
  for (int c = 0; c < 4; ++c) {
    const int b = base + c * 1024;
    f32x4 v0 = src[b];
    f32x4 v1 = src[b + 256];
    f32x4 v2 = src[b + 512];
    f32x4 v3 = src[b + 768];
    __builtin_nontemporal_store(v0, dst + b);
    __builtin_nontemporal_store(v1, dst + b + 256);
    __builtin_nontemporal_store(v2, dst + b + 512);
    __builtin_nontemporal_store(v3, dst + b + 768);
  }
}

extern "C" void kernel_launch(void* const* d_in, const int* in_sizes, int n_in,
                              void* d_out, int out_size, void* d_ws, size_t ws_size,
                              hipStream_t stream) {
  const float* x = (const float*)d_in[0];
  const float* y = (const float*)d_in[1];
  float* out = (float*)d_out;

  float* xb = (float*)d_ws;                 // 786432 floats
  float* yb = xb + SLICE_ELEMS;             // 786432 floats (6 MB total)

  treduce_kernel<<<dim3(2 * SLICE_F4 / 256), dim3(256), 0, stream>>>(x, y, xb, yb);
  gemm_kernel<<<dim3(12, 6, H_DIM), dim3(128), 0, stream>>>(xb, yb, out);
  bcast_kernel<<<dim3(W_F4 / 4096, T_DIM - 1), dim3(256), 0, stream>>>(out);
}

// Round 13
// 182.037 us; speedup vs baseline: 1.1008x; 1.1008x over previous
//
#include <hip/hip_runtime.h>

// x: [T=63, B=1, H=16, S=384, D=128] f32
// y: [T=63, B=1, H=16, D=128, S=384] f32
// out: [63, 1, 16, 384, 384] f32 = broadcast of per-head (mean_t x) @ (mean_t y)
#define T_DIM 63
#define H_DIM 16
#define S_DIM 384
#define D_DIM 128
#define SLICE_ELEMS (H_DIM * S_DIM * D_DIM)        // 786432 floats per t-slice
#define SLICE_F4    (SLICE_ELEMS / 4)              // 196608
#define OUT_TSTRIDE (H_DIM * S_DIM * S_DIM)        // 2359296 floats per t-slice of out
#define W_F4        (OUT_TSTRIDE / 4)              // 589824 float4 per t-slice

typedef float f32x4 __attribute__((ext_vector_type(4)));

// Kernel 1: temporal mean over T for both x and y. Pure read-bound (396 MB).
// nt loads (R7 A/B: nt worth ~15-20% on these streams).
__global__ __launch_bounds__(256) void treduce_kernel(
    const float* __restrict__ x, const float* __restrict__ y,
    float* __restrict__ xb, float* __restrict__ yb) {
  int tid = blockIdx.x * 256 + threadIdx.x;      // 0 .. 2*SLICE_F4-1
  const f32x4* src;
  f32x4* dst;
  if (tid < SLICE_F4) {
    src = reinterpret_cast<const f32x4*>(x) + tid;
    dst = reinterpret_cast<f32x4*>(xb) + tid;
  } else {
    tid -= SLICE_F4;
    src = reinterpret_cast<const f32x4*>(y) + tid;
    dst = reinterpret_cast<f32x4*>(yb) + tid;
  }
  f32x4 acc = (f32x4)0.f;
#pragma unroll 9
  for (int t = 0; t < T_DIM; ++t) {
    f32x4 v = __builtin_nontemporal_load(src + (size_t)t * SLICE_F4);
    acc += v;
  }
  acc *= (1.0f / (float)T_DIM);
  *dst = acc;
}

// Kernel 2: lean 32x32-tile GEMM writing only the t=0 slice. nt w-store
// (R11 A/B: plain stores leave w dirty in the writer XCD's L2; k3's readers
// on other XCDs then pay cross-XCD dirty-line resolution. nt pushes w to
// L3/HBM at write time -> clean k3 reads. -2.7 us measured).
// grid (12,12,16) = 2304 blocks (9/CU, 36 waves/CU), 18 KB LDS.
__global__ __launch_bounds__(256) void gemm_kernel(
    const float* __restrict__ xb, const float* __restrict__ yb,
    float* __restrict__ out) {
  __shared__ float Bs[128][36];

  const int h  = blockIdx.z;
  const int by = blockIdx.y;
  const int bx = blockIdx.x;
  const int t  = threadIdx.x;

  const float* A = xb + (size_t)h * S_DIM * D_DIM;  // [384][128] row-major
  const float* B = yb + (size_t)h * D_DIM * S_DIM;  // [128][384] row-major

  // Stage B tile: 128 rows x 32 cols = 1024 float4, 4 per thread.
#pragma unroll
  for (int it = 0; it < 4; ++it) {
    int l = t + it * 256;
    int k  = l >> 3;         // 8 float4 per row
    int c4 = l & 7;
    float4 v = *reinterpret_cast<const float4*>(B + (size_t)k * S_DIM + bx * 32 + c4 * 4);
    *reinterpret_cast<float4*>(&Bs[k][c4 * 4]) = v;
  }
  __syncthreads();

  const int row = t >> 3;   // 0..31
  const int c4  = t & 7;    // 0..7

  const f32x4* A4 = reinterpret_cast<const f32x4*>(A + (size_t)(by * 32 + row) * D_DIM);

  f32x4 acc = (f32x4)0.f;
#pragma unroll 8
  for (int k4 = 0; k4 < 32; ++k4) {
    f32x4 a4 = A4[k4];
    f32x4 b0 = *reinterpret_cast<const f32x4*>(&Bs[k4 * 4 + 0][c4 * 4]);
    f32x4 b1 = *reinterpret_cast<const f32x4*>(&Bs[k4 * 4 + 1][c4 * 4]);
    f32x4 b2 = *reinterpret_cast<const f32x4*>(&Bs[k4 * 4 + 2][c4 * 4]);
    f32x4 b3 = *reinterpret_cast<const f32x4*>(&Bs[k4 * 4 + 3][c4 * 4]);
    acc += a4.x * b0;
    acc += a4.y * b1;
    acc += a4.z * b2;
    acc += a4.w * b3;
  }

  // Write ONCE into the t=0 slice — nt store.
  float* o = out + (size_t)h * S_DIM * S_DIM
                 + (size_t)(by * 32 + row) * S_DIM + bx * 32 + c4 * 4;
  __builtin_nontemporal_store(acc, reinterpret_cast<f32x4*>(o));
}

// Kernel 3: pure broadcast, fill geometry (t-major). Block (cx, ty) owns a
// linear 16KB chunk of t-slice ty+1; 4 cached reads of the t=0 slice + 4 nt
// stores, 1KB contiguous per store instr per wave. 576 % 8 == 0 -> all 62
// readers of chunk cx land on one XCD (w reads L2-resident after first touch).
// grid = (576, 62), block = 256.
__global__ __launch_bounds__(256) void bcast_kernel(float* __restrict__ out) {
  const int i0 = blockIdx.x * 1024 + threadIdx.x;        // chunk base + lane
  const size_t toff = (size_t)(blockIdx.y + 1) * W_F4;   // t = 1..62
  const f32x4* src = reinterpret_cast<const f32x4*>(out);
  f32x4* dst = reinterpret_cast<f32x4*>(out) + toff;
#pragma unroll
  for (int q = 0; q < 4; ++q) {
    int i = i0 + q * 256;
    f32x4 v = src[i];
    __builtin_nontemporal_store(v, dst + i);
  }
}

extern "C" void kernel_launch(void* const* d_in, const int* in_sizes, int n_in,
                              void* d_out, int out_size, void* d_ws, size_t ws_size,
                              hipStream_t stream) {
  const float* x = (const float*)d_in[0];
  const float* y = (const float*)d_in[1];
  float* out = (float*)d_out;

  float* xb = (float*)d_ws;                 // 786432 floats
  float* yb = xb + SLICE_ELEMS;             // 786432 floats (6 MB total)

  treduce_kernel<<<dim3(2 * SLICE_F4 / 256), dim3(256), 0, stream>>>(x, y, xb, yb);
  gemm_kernel<<<dim3(12, 12, H_DIM), dim3(256), 0, stream>>>(xb, yb, out);
  bcast_kernel<<<dim3(W_F4 / 1024, T_DIM - 1), dim3(256), 0, stream>>>(out);
}